// Round 1
// baseline (2944.623 us; speedup 1.0000x reference)
//
#include <hip/hip_runtime.h>

#define NN 50000
#define NE 800000

__device__ __forceinline__ float silu_f(float x) { return x / (1.0f + __expf(-x)); }

// ---------------------------------------------------------------------------
// K1: x_s = s @ W1_s ; x_v[:,o,c] = sum_u v[:,u,c] * W1_v[u,o]
// block = 256 = 8 nodes x 32 lanes (lane = output channel o)
// ---------------------------------------------------------------------------
__global__ __launch_bounds__(256) void k_node_transform(
    const float* __restrict__ node_feats,
    const float* __restrict__ W1_s,
    const float* __restrict__ W1_v,
    float* __restrict__ x_s,
    float* __restrict__ x_v)
{
    __shared__ float sW1s[32 * 32];
    __shared__ float sW1v[32 * 32];
    __shared__ float sfeat[8][128];
    int t = threadIdx.x;
    for (int i = t; i < 1024; i += 256) { sW1s[i] = W1_s[i]; sW1v[i] = W1_v[i]; }
    int nodeBase = blockIdx.x * 8;
    for (int i = t; i < 8 * 128; i += 256) {
        int nn = nodeBase + (i >> 7);
        sfeat[i >> 7][i & 127] = (nn < NN) ? node_feats[(long)nn * 128 + (i & 127)] : 0.0f;
    }
    __syncthreads();
    int g = t >> 5;
    int o = t & 31;
    int n = nodeBase + g;
    if (n >= NN) return;
    float accs = 0.f, acc0 = 0.f, acc1 = 0.f, acc2 = 0.f;
#pragma unroll
    for (int u = 0; u < 32; ++u) {
        float su  = sfeat[g][u];
        float vu0 = sfeat[g][32 + u * 3 + 0];
        float vu1 = sfeat[g][32 + u * 3 + 1];
        float vu2 = sfeat[g][32 + u * 3 + 2];
        float ws = sW1s[u * 32 + o];
        float wv = sW1v[u * 32 + o];
        accs += su * ws;
        acc0 += vu0 * wv;
        acc1 += vu1 * wv;
        acc2 += vu2 * wv;
    }
    x_s[(long)n * 32 + o] = accs;
    x_v[(long)n * 96 + o * 3 + 0] = acc0;
    x_v[(long)n * 96 + o * 3 + 1] = acc1;
    x_v[(long)n * 96 + o * 3 + 2] = acc2;
}

// ---------------------------------------------------------------------------
// K2: fused edge MLP + tensor-product messages + atomic scatter into a_s/a_v
// block = 256 = 8 groups x 32 lanes; each group handles 4 consecutive edges
// ---------------------------------------------------------------------------
__global__ __launch_bounds__(256) void k_edge(
    const float* __restrict__ edge_embedding,
    const float* __restrict__ edge_attrs,
    const int*   __restrict__ edge_src,
    const int*   __restrict__ edge_dst,
    const float* __restrict__ fc_w1,
    const float* __restrict__ fc_b1,
    const float* __restrict__ fc_w2,
    const float* __restrict__ x_s,
    const float* __restrict__ x_v,
    float* __restrict__ a_s,
    float* __restrict__ a_v)
{
    __shared__ __align__(16) float sw1[8 * 64];
    __shared__ float sb1[64];
    __shared__ __align__(16) float w2t[160 * 68];   // transposed [col][j], pad 68
    __shared__ __align__(16) float h_lds[8][4][64];

    int t = threadIdx.x;
    for (int i = t; i < 8 * 64; i += 256) sw1[i] = fc_w1[i];
    if (t < 64) sb1[t] = fc_b1[t];
    for (int i = t; i < 64 * 160; i += 256) {
        int j = i / 160, col = i % 160;
        w2t[col * 68 + j] = fc_w2[i];
    }
    __syncthreads();

    int lane = t & 31, g = t >> 5;
    long ebase = ((long)blockIdx.x * 8 + g) * 4;

    // phase 1: hidden layer for 4 edges
#pragma unroll
    for (int ee = 0; ee < 4; ++ee) {
        long e = ebase + ee;
        float hA = 0.f, hB = 0.f;
        if (e < NE) {
            hA = sb1[lane]; hB = sb1[lane + 32];
#pragma unroll
            for (int k = 0; k < 8; ++k) {
                float ek = edge_embedding[e * 8 + k];
                hA += ek * sw1[k * 64 + lane];
                hB += ek * sw1[k * 64 + lane + 32];
            }
            hA = silu_f(hA); hB = silu_f(hB);
        }
        h_lds[g][ee][lane] = hA;
        h_lds[g][ee][lane + 32] = hB;
    }
    __syncthreads();

    // phase 2: w = h @ fc_w2, 5 path-weight chunks of 32, 4-edge register block
    float acc[5][4];
#pragma unroll
    for (int p = 0; p < 5; ++p)
#pragma unroll
        for (int ee = 0; ee < 4; ++ee) acc[p][ee] = 0.f;

#pragma unroll
    for (int jc = 0; jc < 16; ++jc) {
        float4 h4[4];
#pragma unroll
        for (int ee = 0; ee < 4; ++ee) h4[ee] = *(const float4*)&h_lds[g][ee][jc * 4];
#pragma unroll
        for (int p = 0; p < 5; ++p) {
            float4 w4 = *(const float4*)&w2t[(p * 32 + lane) * 68 + jc * 4];
#pragma unroll
            for (int ee = 0; ee < 4; ++ee)
                acc[p][ee] += h4[ee].x * w4.x + h4[ee].y * w4.y + h4[ee].z * w4.z + h4[ee].w * w4.w;
        }
    }

    // phase 3: gather, messages, atomic scatter
    const float INV_SQRT3 = 0.5773502691896258f;
    const float INV_SQRT2 = 0.7071067811865476f;
    const float INV_NEI   = 0.25f;  // 1/sqrt(16)

#pragma unroll
    for (int ee = 0; ee < 4; ++ee) {
        long e = ebase + ee;
        if (e >= NE) break;
        int src = edge_src[e], dst = edge_dst[e];
        float sh0 = edge_attrs[e * 4 + 0];
        float s1x = edge_attrs[e * 4 + 1];
        float s1y = edge_attrs[e * 4 + 2];
        float s1z = edge_attrs[e * 4 + 3];
        float xs = x_s[(long)src * 32 + lane];
        const float* xvp = &x_v[(long)src * 96 + lane * 3];
        float xv0 = xvp[0], xv1 = xvp[1], xv2 = xvp[2];
        float w00 = acc[0][ee], w01 = acc[1][ee], w10 = acc[2][ee];
        float w11s = acc[3][ee], w11v = acc[4][ee];

        float ms0 = w00 * xs * sh0;
        float dot = xv0 * s1x + xv1 * s1y + xv2 * s1z;
        float ms1 = w11s * dot * INV_SQRT3;
        float t01 = w01 * xs;
        float t10 = w10 * sh0;
        float k2  = w11v * INV_SQRT2;
        float cx = xv1 * s1z - xv2 * s1y;
        float cy = xv2 * s1x - xv0 * s1z;
        float cz = xv0 * s1y - xv1 * s1x;

        float* asp = &a_s[(long)dst * 64];
        float* avp = &a_v[(long)dst * 288];
        atomicAdd(asp + lane,      ms0 * INV_NEI);
        atomicAdd(asp + 32 + lane, ms1 * INV_NEI);
        atomicAdd(avp + lane * 3 + 0, t01 * s1x * INV_NEI);
        atomicAdd(avp + lane * 3 + 1, t01 * s1y * INV_NEI);
        atomicAdd(avp + lane * 3 + 2, t01 * s1z * INV_NEI);
        atomicAdd(avp + 96 + lane * 3 + 0, t10 * xv0 * INV_NEI);
        atomicAdd(avp + 96 + lane * 3 + 1, t10 * xv1 * INV_NEI);
        atomicAdd(avp + 96 + lane * 3 + 2, t10 * xv2 * INV_NEI);
        atomicAdd(avp + 192 + lane * 3 + 0, k2 * cx * INV_NEI);
        atomicAdd(avp + 192 + lane * 3 + 1, k2 * cy * INV_NEI);
        atomicAdd(avp + 192 + lane * 3 + 2, k2 * cz * INV_NEI);
    }
}

// ---------------------------------------------------------------------------
// K3: y_s = a_s@W2_s + (s x attrs)·Wsc_s ; y_v = a_v@W2_v + (v x attrs)·Wsc_v
//     out = node_feats + [silu(y_s[:32]), y_v * silu(y_s[32:])]
// block = 256 = 8 nodes x 32 lanes (lane = o in 0..31, handles o and o+32)
// ---------------------------------------------------------------------------
__global__ __launch_bounds__(256) void k_node_out(
    const float* __restrict__ node_feats,
    const float* __restrict__ node_attrs,
    const float* __restrict__ a_s,
    const float* __restrict__ a_v,
    const float* __restrict__ W2_s,
    const float* __restrict__ W2_v,
    const float* __restrict__ Wsc_s,
    const float* __restrict__ Wsc_v,
    float* __restrict__ out)
{
    __shared__ float sW2s[64 * 64];
    __shared__ float sW2v[96 * 32];
    __shared__ float sdata[8][496];  // [0,128) feats | [128,144) attrs | [144,208) a_s | [208,496) a_v

    int t = threadIdx.x;
    for (int i = t; i < 64 * 64; i += 256) sW2s[i] = W2_s[i];
    for (int i = t; i < 96 * 32; i += 256) sW2v[i] = W2_v[i];

    int g = t >> 5, o = t & 31;
    int n = blockIdx.x * 8 + g;
    if (n < NN) {
        for (int i = o; i < 496; i += 32) {
            float v;
            if (i < 128)      v = node_feats[(long)n * 128 + i];
            else if (i < 144) v = node_attrs[(long)n * 16 + (i - 128)];
            else if (i < 208) v = a_s[(long)n * 64 + (i - 144)];
            else              v = a_v[(long)n * 288 + (i - 208)];
            sdata[g][i] = v;
        }
    }
    __syncthreads();
    if (n >= NN) return;

    float ys0 = 0.f, ys1 = 0.f, yv0 = 0.f, yv1 = 0.f, yv2 = 0.f;

    // a_s @ W2_s
#pragma unroll 8
    for (int u = 0; u < 64; ++u) {
        float as = sdata[g][144 + u];
        ys0 += as * sW2s[u * 64 + o];
        ys1 += as * sW2s[u * 64 + 32 + o];
    }
    // a_v @ W2_v (per coord)
#pragma unroll 8
    for (int u = 0; u < 96; ++u) {
        float wv = sW2v[u * 32 + o];
        yv0 += sdata[g][208 + u * 3 + 0] * wv;
        yv1 += sdata[g][208 + u * 3 + 1] * wv;
        yv2 += sdata[g][208 + u * 3 + 2] * wv;
    }

    // Wsc bilinear, t-form: t = sum_a attrs[a] * W[u,a,:]
    float att[16];
#pragma unroll
    for (int a = 0; a < 16; ++a) att[a] = sdata[g][128 + a];

    for (int u = 0; u < 32; ++u) {
        const float* Wsp = &Wsc_s[u * 1024 + o];
        const float* Wvp = &Wsc_v[u * 512 + o];
        float t0 = 0.f, t1 = 0.f, tv = 0.f;
#pragma unroll
        for (int a = 0; a < 16; ++a) {
            float aa = att[a];
            t0 += aa * Wsp[a * 64];
            t1 += aa * Wsp[a * 64 + 32];
            tv += aa * Wvp[a * 32];
        }
        float su = sdata[g][u];
        ys0 += su * t0;
        ys1 += su * t1;
        float vv0 = sdata[g][32 + u * 3 + 0];
        float vv1 = sdata[g][32 + u * 3 + 1];
        float vv2 = sdata[g][32 + u * 3 + 2];
        yv0 += vv0 * tv;
        yv1 += vv1 * tv;
        yv2 += vv2 * tv;
    }

    float os   = silu_f(ys0);
    float gate = silu_f(ys1);
    long base = (long)n * 128;
    out[base + o] = sdata[g][o] + os;
    out[base + 32 + o * 3 + 0] = sdata[g][32 + o * 3 + 0] + yv0 * gate;
    out[base + 32 + o * 3 + 1] = sdata[g][32 + o * 3 + 1] + yv1 * gate;
    out[base + 32 + o * 3 + 2] = sdata[g][32 + o * 3 + 2] + yv2 * gate;
}

// ---------------------------------------------------------------------------
extern "C" void kernel_launch(void* const* d_in, const int* in_sizes, int n_in,
                              void* d_out, int out_size, void* d_ws, size_t ws_size,
                              hipStream_t stream) {
    const float* node_feats     = (const float*)d_in[0];
    const float* node_attrs     = (const float*)d_in[1];
    const float* edge_embedding = (const float*)d_in[2];
    const float* edge_attrs     = (const float*)d_in[3];
    const int*   edge_src       = (const int*)d_in[4];
    const int*   edge_dst       = (const int*)d_in[5];
    const float* W1_s  = (const float*)d_in[6];
    const float* W1_v  = (const float*)d_in[7];
    const float* fc_w1 = (const float*)d_in[8];
    const float* fc_b1 = (const float*)d_in[9];
    const float* fc_w2 = (const float*)d_in[10];
    const float* W2_s  = (const float*)d_in[11];
    const float* W2_v  = (const float*)d_in[12];
    const float* Wsc_s = (const float*)d_in[13];
    const float* Wsc_v = (const float*)d_in[14];
    float* out = (float*)d_out;

    float* ws  = (float*)d_ws;
    float* x_s = ws;                    // NN*32
    float* x_v = ws + (long)NN * 32;    // NN*96
    float* a_s = ws + (long)NN * 128;   // NN*64
    float* a_v = ws + (long)NN * 192;   // NN*288

    hipMemsetAsync(a_s, 0, (size_t)NN * 352 * sizeof(float), stream);
    k_node_transform<<<(NN + 7) / 8, 256, 0, stream>>>(node_feats, W1_s, W1_v, x_s, x_v);
    k_edge<<<(NE + 31) / 32, 256, 0, stream>>>(edge_embedding, edge_attrs, edge_src, edge_dst,
                                               fc_w1, fc_b1, fc_w2, x_s, x_v, a_s, a_v);
    k_node_out<<<(NN + 7) / 8, 256, 0, stream>>>(node_feats, node_attrs, a_s, a_v,
                                                 W2_s, W2_v, Wsc_s, Wsc_v, out);
}

// Round 2
// 1109.078 us; speedup vs baseline: 2.6550x; 2.6550x over previous
//
#include <hip/hip_runtime.h>

#define NN 50000
#define NE 800000

__device__ __forceinline__ float silu_f(float x) { return x / (1.0f + __expf(-x)); }

// ---------------------------------------------------------------------------
// K1: x_s = s @ W1_s ; x_v planar: x_v[n*96 + c*32 + o] = sum_u v[n][u][c]*W1_v[u][o]
// ---------------------------------------------------------------------------
__global__ __launch_bounds__(256) void k_node_transform(
    const float* __restrict__ node_feats,
    const float* __restrict__ W1_s,
    const float* __restrict__ W1_v,
    float* __restrict__ x_s,
    float* __restrict__ x_v)
{
    __shared__ float sW1s[32 * 32];
    __shared__ float sW1v[32 * 32];
    __shared__ float sfeat[8][128];
    int t = threadIdx.x;
    for (int i = t; i < 1024; i += 256) { sW1s[i] = W1_s[i]; sW1v[i] = W1_v[i]; }
    int nodeBase = blockIdx.x * 8;
    for (int i = t; i < 8 * 128; i += 256) {
        int nn = nodeBase + (i >> 7);
        sfeat[i >> 7][i & 127] = (nn < NN) ? node_feats[(long)nn * 128 + (i & 127)] : 0.0f;
    }
    __syncthreads();
    int g = t >> 5, o = t & 31;
    int n = nodeBase + g;
    if (n >= NN) return;
    float accs = 0.f, acc0 = 0.f, acc1 = 0.f, acc2 = 0.f;
#pragma unroll
    for (int u = 0; u < 32; ++u) {
        float su  = sfeat[g][u];
        float vu0 = sfeat[g][32 + u * 3 + 0];
        float vu1 = sfeat[g][32 + u * 3 + 1];
        float vu2 = sfeat[g][32 + u * 3 + 2];
        float ws = sW1s[u * 32 + o];
        float wv = sW1v[u * 32 + o];
        accs += su * ws;
        acc0 += vu0 * wv;
        acc1 += vu1 * wv;
        acc2 += vu2 * wv;
    }
    x_s[(long)n * 32 + o] = accs;
    x_v[(long)n * 96 +      o] = acc0;
    x_v[(long)n * 96 + 32 + o] = acc1;
    x_v[(long)n * 96 + 64 + o] = acc2;
}

// ---------------------------------------------------------------------------
// CSR build: histogram -> single-block scan -> fill
// ---------------------------------------------------------------------------
__global__ __launch_bounds__(256) void k_hist(const int* __restrict__ edge_dst,
                                              int* __restrict__ counts)
{
    int e = blockIdx.x * 256 + threadIdx.x;
    if (e < NE) atomicAdd(&counts[edge_dst[e]], 1);
}

__global__ __launch_bounds__(1024) void k_scan(const int* __restrict__ counts,
                                               int* __restrict__ row_ptr,
                                               int* __restrict__ cursor)
{
    __shared__ int wsum[16];
    __shared__ int carry_s;
    int t = threadIdx.x;
    int lane = t & 63, w = t >> 6;
    if (t == 0) carry_s = 0;
    __syncthreads();
    for (int base = 0; base < NN; base += 1024) {
        int i = base + t;
        int v = (i < NN) ? counts[i] : 0;
        int s = v;
#pragma unroll
        for (int d = 1; d < 64; d <<= 1) {
            int o = __shfl_up(s, d, 64);
            if (lane >= d) s += o;
        }
        if (lane == 63) wsum[w] = s;
        __syncthreads();
        if (w == 0) {
            int ws = (lane < 16) ? wsum[lane] : 0;
#pragma unroll
            for (int d = 1; d < 16; d <<= 1) {
                int o = __shfl_up(ws, d, 64);
                if (lane >= d) ws += o;
            }
            if (lane < 16) wsum[lane] = ws;
        }
        __syncthreads();
        int excl = (s - v) + ((w > 0) ? wsum[w - 1] : 0) + carry_s;
        if (i < NN) { row_ptr[i] = excl; cursor[i] = excl; }
        int total = wsum[15];
        __syncthreads();
        if (t == 0) carry_s += total;
        __syncthreads();
    }
    if (t == 0) row_ptr[NN] = carry_s;
}

__global__ __launch_bounds__(256) void k_fill(const int* __restrict__ edge_dst,
                                              int* __restrict__ cursor,
                                              int* __restrict__ edge_ids)
{
    int e = blockIdx.x * 256 + threadIdx.x;
    if (e < NE) {
        int slot = atomicAdd(&cursor[edge_dst[e]], 1);
        edge_ids[slot] = e;
    }
}

// ---------------------------------------------------------------------------
// K2: fused gather: per dst node, loop CSR edge list; edge MLP + messages
// accumulated in registers (NO atomics), then fused K3 epilogue.
// block = 256 = 8 groups x 32 lanes, group = one node. 4-edge inner blocking.
// ---------------------------------------------------------------------------
__global__ __launch_bounds__(256) void k_gather(
    const float* __restrict__ edge_embedding,
    const float* __restrict__ edge_attrs,
    const int*   __restrict__ edge_src,
    const float* __restrict__ fc_w1,
    const float* __restrict__ fc_b1,
    const float* __restrict__ fc_w2,
    const float* __restrict__ x_s,
    const float* __restrict__ x_v,
    const int*   __restrict__ row_ptr,
    const int*   __restrict__ edge_ids,
    const float* __restrict__ node_feats,
    const float* __restrict__ node_attrs,
    const float* __restrict__ W2_s,
    const float* __restrict__ W2_v,
    const float* __restrict__ Wsc_s,
    const float* __restrict__ Wsc_v,
    float* __restrict__ out)
{
    __shared__ __align__(16) float sw1[8 * 64];     // 2 KB
    __shared__ float sb1[64];
    __shared__ __align__(16) float sw2[64 * 160];   // 40 KB, natural layout [j][col]
    __shared__ __align__(16) float hbuf[8][256];    // 8 KB  (4 edges x 64 hidden) / reused for feats+attrs
    __shared__ float asbuf[8][64];                  // 2 KB
    __shared__ float avbuf[8][288];                 // 9 KB

    int t = threadIdx.x;
    for (int i = t; i < 8 * 64; i += 256) sw1[i] = fc_w1[i];
    if (t < 64) sb1[t] = fc_b1[t];
    for (int i = t; i < 64 * 160; i += 256) sw2[i] = fc_w2[i];
    __syncthreads();

    int g = t >> 5, lane = t & 31;
    int n = blockIdx.x * 8 + g;
    if (n >= NN) return;

    int start = row_ptr[n];
    int end   = row_ptr[n + 1];

    float as0 = 0.f, as1 = 0.f;
    float av[9];
#pragma unroll
    for (int p = 0; p < 9; ++p) av[p] = 0.f;

    float* hb = &hbuf[g][0];
    const float INV_SQRT3 = 0.5773502691896258f;
    const float INV_SQRT2 = 0.7071067811865476f;
    const float INV_NEI   = 0.25f;

    for (int i = start; i < end; i += 4) {
        int ne = end - i;          // >= 1
        int eid[4];
#pragma unroll
        for (int k = 0; k < 4; ++k) eid[k] = edge_ids[(k < ne) ? (i + k) : i];

        // ---- hidden layer for 4 edges (dummies duplicate edge 0: safe values)
        float em[4][8];
#pragma unroll
        for (int k = 0; k < 4; ++k) {
            *(float4*)&em[k][0] = *(const float4*)&edge_embedding[(long)eid[k] * 8];
            *(float4*)&em[k][4] = *(const float4*)&edge_embedding[(long)eid[k] * 8 + 4];
        }
#pragma unroll
        for (int k = 0; k < 4; ++k) {
            float h0 = sb1[lane], h1 = sb1[lane + 32];
#pragma unroll
            for (int q = 0; q < 8; ++q) {
                float e = em[k][q];
                h0 += e * sw1[q * 64 + lane];
                h1 += e * sw1[q * 64 + lane + 32];
            }
            hb[k * 64 + lane]      = silu_f(h0);
            hb[k * 64 + 32 + lane] = silu_f(h1);
        }
        // same-wave LDS RAW: in-order DS pipe + compiler waitcnt; no barrier
        // (barrier here would be illegal: divergent trip counts across groups)

        // ---- w = h @ fc_w2 : 5 path columns per lane, 4-edge register block
        float acc[5][4];
#pragma unroll
        for (int p = 0; p < 5; ++p)
#pragma unroll
            for (int k = 0; k < 4; ++k) acc[p][k] = 0.f;

#pragma unroll 4
        for (int j = 0; j < 64; ++j) {
            const float* wr = &sw2[j * 160 + lane];
            float w0 = wr[0], w1 = wr[32], w2 = wr[64], w3 = wr[96], w4 = wr[128];
#pragma unroll
            for (int k = 0; k < 4; ++k) {
                float hj = hb[k * 64 + j];
                acc[0][k] += hj * w0;
                acc[1][k] += hj * w1;
                acc[2][k] += hj * w2;
                acc[3][k] += hj * w3;
                acc[4][k] += hj * w4;
            }
        }

        // ---- messages, register accumulate
#pragma unroll
        for (int k = 0; k < 4; ++k) {
            if (k >= ne) break;
            int e = eid[k];
            int src = edge_src[e];
            float4 at = *(const float4*)&edge_attrs[(long)e * 4];
            float xs  = x_s[(long)src * 32 + lane];
            float xv0 = x_v[(long)src * 96 +      lane];
            float xv1 = x_v[(long)src * 96 + 32 + lane];
            float xv2 = x_v[(long)src * 96 + 64 + lane];
            float w00 = acc[0][k], w01 = acc[1][k], w10 = acc[2][k];
            float w11s = acc[3][k], w11v = acc[4][k];

            as0 += w00 * xs * at.x;
            float dot = xv0 * at.y + xv1 * at.z + xv2 * at.w;
            as1 += w11s * dot * INV_SQRT3;
            float t01 = w01 * xs;
            av[0] += t01 * at.y; av[1] += t01 * at.z; av[2] += t01 * at.w;
            float t10 = w10 * at.x;
            av[3] += t10 * xv0; av[4] += t10 * xv1; av[5] += t10 * xv2;
            float k2 = w11v * INV_SQRT2;
            av[6] += k2 * (xv1 * at.w - xv2 * at.z);
            av[7] += k2 * (xv2 * at.y - xv0 * at.w);
            av[8] += k2 * (xv0 * at.z - xv1 * at.y);
        }
    }

    // ---- stage accumulators (group-private LDS, same-wave only)
    asbuf[g][lane]      = as0 * INV_NEI;
    asbuf[g][32 + lane] = as1 * INV_NEI;
#pragma unroll
    for (int p = 0; p < 3; ++p)
#pragma unroll
        for (int c = 0; c < 3; ++c)
            avbuf[g][(p * 32 + lane) * 3 + c] = av[p * 3 + c] * INV_NEI;

    // ---- stage this node's feats + attrs into hbuf (reuse)
    *(float4*)&hb[lane * 4] = *(const float4*)&node_feats[(long)n * 128 + lane * 4];
    if (lane < 16) hb[128 + lane] = node_attrs[(long)n * 16 + lane];

    // ---- fused epilogue (K3): W2 GEMVs + Wsc bilinear (t-form) + gate + residual
    int o = lane;
    float ys0 = 0.f, ys1 = 0.f, yv0 = 0.f, yv1 = 0.f, yv2 = 0.f;

#pragma unroll 8
    for (int u = 0; u < 64; ++u) {
        float as = asbuf[g][u];
        ys0 += as * W2_s[u * 64 + o];
        ys1 += as * W2_s[u * 64 + 32 + o];
    }
#pragma unroll 8
    for (int u = 0; u < 96; ++u) {
        float wv = W2_v[u * 32 + o];
        yv0 += avbuf[g][u * 3 + 0] * wv;
        yv1 += avbuf[g][u * 3 + 1] * wv;
        yv2 += avbuf[g][u * 3 + 2] * wv;
    }

    float att[16];
#pragma unroll
    for (int a = 0; a < 16; ++a) att[a] = hb[128 + a];

    for (int u = 0; u < 32; ++u) {
        const float* Wsp = &Wsc_s[u * 1024 + o];
        const float* Wvp = &Wsc_v[u * 512 + o];
        float t0 = 0.f, t1 = 0.f, tv = 0.f;
#pragma unroll
        for (int a = 0; a < 16; ++a) {
            float aa = att[a];
            t0 += aa * Wsp[a * 64];
            t1 += aa * Wsp[a * 64 + 32];
            tv += aa * Wvp[a * 32];
        }
        float su = hb[u];
        ys0 += su * t0;
        ys1 += su * t1;
        float vv0 = hb[32 + u * 3 + 0];
        float vv1 = hb[32 + u * 3 + 1];
        float vv2 = hb[32 + u * 3 + 2];
        yv0 += vv0 * tv;
        yv1 += vv1 * tv;
        yv2 += vv2 * tv;
    }

    float os   = silu_f(ys0);
    float gate = silu_f(ys1);
    long base = (long)n * 128;
    out[base + o] = hb[o] + os;
    out[base + 32 + o * 3 + 0] = hb[32 + o * 3 + 0] + yv0 * gate;
    out[base + 32 + o * 3 + 1] = hb[32 + o * 3 + 1] + yv1 * gate;
    out[base + 32 + o * 3 + 2] = hb[32 + o * 3 + 2] + yv2 * gate;
}

// ---------------------------------------------------------------------------
extern "C" void kernel_launch(void* const* d_in, const int* in_sizes, int n_in,
                              void* d_out, int out_size, void* d_ws, size_t ws_size,
                              hipStream_t stream) {
    const float* node_feats     = (const float*)d_in[0];
    const float* node_attrs     = (const float*)d_in[1];
    const float* edge_embedding = (const float*)d_in[2];
    const float* edge_attrs     = (const float*)d_in[3];
    const int*   edge_src       = (const int*)d_in[4];
    const int*   edge_dst       = (const int*)d_in[5];
    const float* W1_s  = (const float*)d_in[6];
    const float* W1_v  = (const float*)d_in[7];
    const float* fc_w1 = (const float*)d_in[8];
    const float* fc_b1 = (const float*)d_in[9];
    const float* fc_w2 = (const float*)d_in[10];
    const float* W2_s  = (const float*)d_in[11];
    const float* W2_v  = (const float*)d_in[12];
    const float* Wsc_s = (const float*)d_in[13];
    const float* Wsc_v = (const float*)d_in[14];
    float* out = (float*)d_out;

    float* ws  = (float*)d_ws;
    float* x_s = ws;                       // NN*32 floats
    float* x_v = ws + (long)NN * 32;       // NN*96 floats (planar)
    int* ibase    = (int*)(ws + (long)NN * 128);
    int* counts   = ibase;                 // NN
    int* row_ptr  = ibase + NN;            // NN+1
    int* cursor   = ibase + 2 * NN + 1;    // NN
    int* edge_ids = ibase + 3 * NN + 1;    // NE

    hipMemsetAsync(counts, 0, (size_t)NN * sizeof(int), stream);
    k_hist<<<(NE + 255) / 256, 256, 0, stream>>>(edge_dst, counts);
    k_node_transform<<<(NN + 7) / 8, 256, 0, stream>>>(node_feats, W1_s, W1_v, x_s, x_v);
    k_scan<<<1, 1024, 0, stream>>>(counts, row_ptr, cursor);
    k_fill<<<(NE + 255) / 256, 256, 0, stream>>>(edge_dst, cursor, edge_ids);
    k_gather<<<(NN + 7) / 8, 256, 0, stream>>>(edge_embedding, edge_attrs, edge_src,
                                               fc_w1, fc_b1, fc_w2, x_s, x_v,
                                               row_ptr, edge_ids,
                                               node_feats, node_attrs,
                                               W2_s, W2_v, Wsc_s, Wsc_v, out);
}